// Round 9
// baseline (221.379 us; speedup 1.0000x reference)
//
#include <hip/hip_runtime.h>
#include <hip/hip_bf16.h>
#include <math.h>

// Sizes (fixed by the problem)
#define BATCH 16
#define TLEN  512
#define HD    16     // per-direction hidden
#define HID   32     // 2*HD

typedef float v2f __attribute__((ext_vector_type(2)));
typedef unsigned u2v __attribute__((ext_vector_type(2)));

// Static device scratch — avoids any assumption about ws_size.
__device__ float g_outBT[BATCH * TLEN * HID];   // 1 MB
__device__ float g_preA [BATCH * TLEN * HID];   // 1 MB
__device__ float g_Ct   [BATCH * HID * TLEN];   // 1 MB
__device__ float g_un   [BATCH * TLEN];
__device__ float g_w2d  [BATCH * TLEN];
__device__ float g_accum[BATCH];                // zero-initialized, self-resetting
__device__ int   g_cnt  [BATCH];                // zero-initialized, self-resetting

__device__ __forceinline__ float sigm_(float x) {
    return 1.0f / (1.0f + __expf(-x));
}

__device__ __forceinline__ float ex2_(float x) {
#if __has_builtin(__builtin_amdgcn_exp2f)
    return __builtin_amdgcn_exp2f(x);     // raw v_exp_f32 (2^x)
#else
    return exp2f(x);
#endif
}
__device__ __forceinline__ float rcp_(float x) {
#if __has_builtin(__builtin_amdgcn_rcpf)
    return __builtin_amdgcn_rcpf(x);      // raw v_rcp_f32 — avoids IEEE div chain
#else
    return 1.0f / x;
#endif
}

// ---------------------------------------------------------------------------
// K1: bidirectional LSTM, round 15 — dependent-chain surgery.
// Round-8 post-mortem: 384 cyc/step vs ~135 cyc issue and a ~20-op serial
// chain -> single-wave dependent-VALU hop costs ~8-10 cyc (no co-resident
// waves to fill the gap). Lever = CHAIN DEPTH. Changes (all algebraically
// exact vs the round-8 kernel, which passed absmax=0):
//  - Product trick: ai*ag = (g&1)? y1*y3 : y0*y2 (the {i,g} role pair is
//    always {even rows} or {odd rows} as a set; mul commutes). Kills the
//    12-cndmask role ladder; af/ao are 2-level selects.
//  - y3 = permlane32(y1) (not permlane16(y2)): frees y2 earlier for m02.
//  - hn = fmaf(-(ao+ao), inv2, ao): ao+ao runs parallel with the tanh
//    trans-chain; one fewer dependent level at the step tail.
//  - 8-accumulator dot: depth 2 fma + 3 adds (was 4 fma + 2 adds).
// Layout unchanged: 1 chain/wave (32 blocks), lane r = gate row (g=r>>4,
// u=r&15), dir wave-uniform; folded exp2 scales; c scaled by 2*log2e.
// ---------------------------------------------------------------------------
__global__ __launch_bounds__(64, 1) void k1_lstm(
    const float* __restrict__ sent,   // [B,T]
    const float* __restrict__ h0,     // [2,B,16]
    const float* __restrict__ c0,     // [2,B,16]
    const float* __restrict__ Wih_f, const float* __restrict__ Whh_f, const float* __restrict__ b_f,
    const float* __restrict__ Wih_b, const float* __restrict__ Whh_b, const float* __restrict__ b_b)
{
    const int blk = blockIdx.x;       // 0..31
    const int dir = blk >> 4;         // 0 fwd, 1 bwd (wave-uniform)
    const int b   = blk & 15;         // batch
    const int r   = threadIdx.x;      // gate row 0..63
    const int u   = r & 15;           // unit
    const int g   = r >> 4;           // 0=i,1=f,2=g,3=o

    const float* Wih  = dir ? Wih_b : Wih_f;
    const float* Whh  = dir ? Whh_b : Whh_f;
    const float* bias = dir ? b_b   : b_f;

    const float L2E = 1.4426950408889634f;
    // fold the exp2 argument scale into this gate row's weights:
    //   sigm rows (i,f,o): p' = -log2e * p  -> sigm(p) = rcp(2^p' + 1)
    //   tanh row  (g):     p' = 2*log2e * p -> tanh(p) = 1 - 2*rcp(2^p' + 1)
    const bool  isg = (g == 2);
    const float sc  = isg ? (2.0f * L2E) : (-L2E);
    // act = fma(mm, rcp(2^p' + 1), aa); g row emits 2log2e*tanh directly.
    const float mm  = isg ? (-4.0f * L2E) : 1.0f;
    const float aa  = isg ? ( 2.0f * L2E) : 0.0f;

    // 16 scalar recurrent weights; wh<k> multiplies h[(u-k)&15].
    float wh0, wh1, wh2, wh3, wh4, wh5, wh6, wh7,
          wh8, wh9, wh10, wh11, wh12, wh13, wh14, wh15;
#define LDW(K) { const int m = (u - (K)) & 15; wh##K = Whh[r * 16 + m] * sc; }
    LDW(0)  LDW(1)  LDW(2)  LDW(3)  LDW(4)  LDW(5)  LDW(6)  LDW(7)
    LDW(8)  LDW(9)  LDW(10) LDW(11) LDW(12) LDW(13) LDW(14) LDW(15)
#undef LDW
    const float wx = Wih[r] * sc;
    const float bb = bias[r] * sc;

    const bool gb0 = (g & 1) != 0;
    const bool gb1 = (g & 2) != 0;

    // replicated per-row state: h[u], and c[u] scaled by 2*log2e
    float hn = h0[dir * (BATCH * HD) + b * HD + u];
    float cc = c0[dir * (BATCH * HD) + b * HD + u] * (2.0f * L2E);

    const float* srow = sent + b * TLEN;
    float* obase = g_outBT + (size_t)b * TLEN * HID + dir * HD + u;
    const int sg = dir ? -HID : HID;    // per-step store stride (elements)

    // 8-step chunks, double-buffered x (two float4 per chunk)
    float4 xcA = *(const float4*)(srow + (dir ? (TLEN - 8) : 0));
    float4 xcB = *(const float4*)(srow + (dir ? (TLEN - 4) : 4));
    for (int tb = 0; tb < TLEN; tb += 8) {
        float4 xnA = xcA, xnB = xcB;
        if (tb + 8 < TLEN) {
            const int nb = dir ? (TLEN - 16 - tb) : (tb + 8);
            xnA = *(const float4*)(srow + nb);
            xnB = *(const float4*)(srow + nb + 4);
        }
        // chunk-order x values (bwd consumes the chunk reversed)
        float xs[8];
        if (dir) {
            xs[0] = xcB.w; xs[1] = xcB.z; xs[2] = xcB.y; xs[3] = xcB.x;
            xs[4] = xcA.w; xs[5] = xcA.z; xs[6] = xcA.y; xs[7] = xcA.x;
        } else {
            xs[0] = xcA.x; xs[1] = xcA.y; xs[2] = xcA.z; xs[3] = xcA.w;
            xs[4] = xcB.x; xs[5] = xcB.y; xs[6] = xcB.z; xs[7] = xcB.w;
        }
        // hoisted x-base: independent of the recurrence, off the serial chain
        float pb[8];
        #pragma unroll
        for (int s2 = 0; s2 < 8; ++s2) pb[s2] = fmaf(xs[s2], wx, bb);

        float hsave[8];

        #pragma unroll
        for (int s2 = 0; s2 < 8; ++s2) {
            // 15 independent rotations of this row's h copy (literal DPP ctl)
            const int r0i = __float_as_int(hn);
            float rot[16];
            rot[0] = hn;
#define ROT(K) rot[K] = __int_as_float( \
                __builtin_amdgcn_mov_dpp(r0i, 0x120 + K, 0xF, 0xF, true));
            ROT(1)  ROT(2)  ROT(3)  ROT(4)  ROT(5)  ROT(6)  ROT(7)
            ROT(8)  ROT(9)  ROT(10) ROT(11) ROT(12) ROT(13) ROT(14) ROT(15)
#undef ROT

            // 16-term dot, 8 accumulators: depth 2 fma + 3 add levels
            float a0 = fmaf(rot[0], wh0, pb[s2]);
            float a1 = rot[1] * wh1;
            float a2 = rot[2] * wh2;
            float a3 = rot[3] * wh3;
            float a4 = rot[4] * wh4;
            float a5 = rot[5] * wh5;
            float a6 = rot[6] * wh6;
            float a7 = rot[7] * wh7;
            a0 = fmaf(rot[8],  wh8,  a0);
            a1 = fmaf(rot[9],  wh9,  a1);
            a2 = fmaf(rot[10], wh10, a2);
            a3 = fmaf(rot[11], wh11, a3);
            a4 = fmaf(rot[12], wh12, a4);
            a5 = fmaf(rot[13], wh13, a5);
            a6 = fmaf(rot[14], wh14, a6);
            a7 = fmaf(rot[15], wh15, a7);
            const float b0 = a0 + a1, b1 = a2 + a3, b2 = a4 + a5, b3 = a6 + a7;
            const float p  = (b0 + b1) + (b2 + b3);  // pre-act, scale folded

            // activation: act = fma(mm, rcp(2^p + 1), aa)
            const float e   = ex2_(p);
            const float iv  = rcp_(e + 1.0f);
            const float act = fmaf(mm, iv, aa);
            // i/f/o rows: sigm(p).  g row: 2log2e * tanh(p).

            // gather: y_k = act of row g^k (permlane, VALU-pipe)
            float y1, y2, y3;
            {
                const unsigned a_i = (unsigned)__float_as_int(act);
                u2v q16 = __builtin_amdgcn_permlane16_swap(a_i, a_i, false, false);
                const unsigned y1i = gb0 ? q16[0] : q16[1];
                y1 = __int_as_float((int)y1i);
                u2v q32 = __builtin_amdgcn_permlane32_swap(a_i, a_i, false, false);
                y2 = __int_as_float((int)(gb1 ? q32[0] : q32[1]));
                u2v q48 = __builtin_amdgcn_permlane32_swap(y1i, y1i, false, false);
                y3 = __int_as_float((int)(gb1 ? q48[0] : q48[1]));
            }
            const float y0 = act;

            // roles via products + 2-level selects (verified per-lane):
            //   ai*ag = gb0 ? y1*y3 : y0*y2
            //   af    = gb0 ? (gb1 ? y2 : y0) : (gb1 ? y3 : y1)
            //   ao    = gb0 ? (gb1 ? y0 : y2) : (gb1 ? y1 : y3)
            const float m02 = y0 * y2;
            const float m13 = y1 * y3;
            const float P   = gb0 ? m13 : m02;
            const float af  = gb0 ? (gb1 ? y2 : y0) : (gb1 ? y3 : y1);
            const float ao  = gb0 ? (gb1 ? y0 : y2) : (gb1 ? y1 : y3);

            // c' = af*c' + P   (c' = 2log2e * c; P = ai * 2log2e*tanh_g)
            cc = fmaf(af, cc, P);
            // hn = ao * (1 - 2*rcp(2^c' + 1)) = fma(-(ao+ao), inv2, ao)
            const float e2   = ex2_(cc);
            const float ao2  = ao + ao;          // parallel with e2 chain
            const float inv2 = rcp_(e2 + 1.0f);
            hn = fmaf(-ao2, inv2, ao);
            hsave[s2] = hn;
        }

        // batched store: g==0 rows (16 lanes), one exec toggle per 8 steps
        if (g == 0) {
            float* bp = obase + (size_t)(dir ? (TLEN - 1 - tb) : tb) * HID;
            #pragma unroll
            for (int s2 = 0; s2 < 8; ++s2) bp[s2 * sg] = hsave[s2];
        }
        xcA = xnA; xcB = xnB;
    }
}

// ---------------------------------------------------------------------------
// K2: projections. Thread per (b,t). W1 etc. staged in LDS.
// ---------------------------------------------------------------------------
__global__ __launch_bounds__(256) void k2_proj(
    const float* __restrict__ W1,     // [32,64]
    const float* __restrict__ b1,     // [32]
    const float* __restrict__ Wu,     // [32]
    const float* __restrict__ bu,     // [1]
    const float* __restrict__ Wout)   // [32]
{
    __shared__ float w1s[HID * 64];
    __shared__ float b1s[HID], wus[HID], wos[HID];
    const int tid = threadIdx.x;
    for (int k = tid; k < HID * 64; k += 256) w1s[k] = W1[k];
    if (tid < HID) { b1s[tid] = b1[tid]; wus[tid] = Wu[tid]; wos[tid] = Wout[tid]; }
    __syncthreads();

    const int g = blockIdx.x * 256 + tid;    // 0..8191
    const int b = g >> 9;
    const int t = g & (TLEN - 1);

    float o[32];
    const float4* src = (const float4*)(g_outBT + (size_t)g * HID);
    #pragma unroll
    for (int qq = 0; qq < 8; ++qq) {
        float4 v = src[qq];
        o[qq * 4 + 0] = v.x; o[qq * 4 + 1] = v.y; o[qq * 4 + 2] = v.z; o[qq * 4 + 3] = v.w;
    }

    float* pa = g_preA + (size_t)g * HID;
    float* ct = g_Ct + (size_t)b * HID * TLEN + t;
    #pragma unroll 4
    for (int h = 0; h < HID; ++h) {
        float a = b1s[h], cacc = 0.f;
        const float* wr = &w1s[h * 64];
        #pragma unroll
        for (int k = 0; k < HID; ++k) {
            a    = fmaf(o[k], wr[k], a);
            cacc = fmaf(o[k], wr[32 + k], cacc);
        }
        pa[h] = a;
        ct[(size_t)h * TLEN] = cacc;
    }

    float ua = 0.f, wa = 0.f;
    #pragma unroll
    for (int k = 0; k < HID; ++k) { ua = fmaf(o[k], wus[k], ua); wa = fmaf(o[k], wos[k], wa); }
    g_un[g]  = ua + bu[0];
    g_w2d[g] = wa;
}

// ---------------------------------------------------------------------------
// K34: S[b,i] = sum_j sum_h relu(preA[b,i,h] + Ct[b,h,j]) * W2[h]
//      prob[b,i] = sigmoid((S - diag_i + 511*b2)/100 + un[b,i])
//      out[b] = sum_i prob[b,i]*w2d[b,i] / 512 + bout
// ---------------------------------------------------------------------------
__global__ __launch_bounds__(256) void k34_binary(
    const float* __restrict__ W2,     // [32]
    const float* __restrict__ b2p,    // [1]
    const float* __restrict__ boutp,  // [1]
    float* __restrict__ out)          // [16]
{
    const int b     = blockIdx.x >> 6;
    const int itile = blockIdx.x & 63;
    const int i0    = itile * 8;
    const int tid   = threadIdx.x;

    __shared__ float pa[8][HID];
    __shared__ float w2s[HID];
    __shared__ float redw[4][8];

    pa[tid >> 5][tid & 31] = g_preA[((size_t)b * TLEN + i0 + (tid >> 5)) * HID + (tid & 31)];
    if (tid < HID) w2s[tid] = W2[tid];
    __syncthreads();

    const float* ctb = g_Ct + (size_t)b * HID * TLEN;
    const int j0 = tid, j1 = tid + 256;

    float acc[8];
    #pragma unroll
    for (int ii = 0; ii < 8; ++ii) acc[ii] = 0.f;

    #pragma unroll 8
    for (int h = 0; h < HID; ++h) {
        const float c0v = ctb[(size_t)h * TLEN + j0];
        const float c1v = ctb[(size_t)h * TLEN + j1];
        const float w   = w2s[h];
        #pragma unroll
        for (int ii = 0; ii < 8; ++ii) {
            const float p = pa[ii][h];
            acc[ii] = fmaf(fmaxf(p + c0v, 0.f), w, acc[ii]);
            acc[ii] = fmaf(fmaxf(p + c1v, 0.f), w, acc[ii]);
        }
    }

    #pragma unroll
    for (int ii = 0; ii < 8; ++ii) {
        float v = acc[ii];
        #pragma unroll
        for (int off = 32; off >= 1; off >>= 1) v += __shfl_down(v, off);
        if ((tid & 63) == 0) redw[tid >> 6][ii] = v;
    }
    __syncthreads();

    if (tid < 8) {
        const float S = redw[0][tid] + redw[1][tid] + redw[2][tid] + redw[3][tid];
        const int i = i0 + tid;
        float diag = 0.f;
        #pragma unroll
        for (int h = 0; h < HID; ++h)
            diag = fmaf(fmaxf(pa[tid][h] + ctb[(size_t)h * TLEN + i], 0.f), w2s[h], diag);
        const float b2 = b2p[0];
        const float s = (S - diag + (float)(TLEN - 1) * b2) * 0.01f + g_un[(size_t)b * TLEN + i];
        float contrib = sigm_(s) * g_w2d[(size_t)b * TLEN + i];
        contrib += __shfl_down(contrib, 4);
        contrib += __shfl_down(contrib, 2);
        contrib += __shfl_down(contrib, 1);
        if (tid == 0) {
            atomicAdd(&g_accum[b], contrib);
            __threadfence();
            int old = atomicAdd(&g_cnt[b], 1);
            if (old == 63) {
                __threadfence();
                float tot = atomicExch(&g_accum[b], 0.0f);
                out[b] = tot * (1.0f / (float)TLEN) + boutp[0];
                atomicExch(&g_cnt[b], 0);
            }
        }
    }
}

extern "C" void kernel_launch(void* const* d_in, const int* in_sizes, int n_in,
                              void* d_out, int out_size, void* d_ws, size_t ws_size,
                              hipStream_t stream) {
    const float* sent  = (const float*)d_in[0];
    const float* h0    = (const float*)d_in[1];
    const float* c0    = (const float*)d_in[2];
    const float* Wih_f = (const float*)d_in[3];
    const float* Whh_f = (const float*)d_in[4];
    const float* b_f   = (const float*)d_in[5];
    const float* Wih_b = (const float*)d_in[6];
    const float* Whh_b = (const float*)d_in[7];
    const float* b_b   = (const float*)d_in[8];
    const float* W1    = (const float*)d_in[9];
    const float* b1    = (const float*)d_in[10];
    const float* W2    = (const float*)d_in[11];
    const float* b2    = (const float*)d_in[12];
    const float* Wu    = (const float*)d_in[13];
    const float* bu    = (const float*)d_in[14];
    const float* Wout  = (const float*)d_in[15];
    const float* bout  = (const float*)d_in[16];

    k1_lstm<<<32, 64, 0, stream>>>(sent, h0, c0, Wih_f, Whh_f, b_f,
                                   Wih_b, Whh_b, b_b);
    k2_proj<<<32, 256, 0, stream>>>(W1, b1, Wu, bu, Wout);
    k34_binary<<<1024, 256, 0, stream>>>(W2, b2, bout, (float*)d_out);
}